// Round 1
// baseline (349.046 us; speedup 1.0000x reference)
//
#include <hip/hip_runtime.h>

// ---------------- types / helpers ----------------
typedef __bf16 bf16x8 __attribute__((ext_vector_type(8)));
typedef float  f32x4  __attribute__((ext_vector_type(4)));

#define MFMA(a, b, c) __builtin_amdgcn_mfma_f32_16x16x32_bf16((a), (b), (c), 0, 0, 0)

#define BB 4
#define TT 2048
#define SS 512
#define DM 1024
#define NH 16
#define HD 64

__device__ __forceinline__ unsigned short f2b(float f) {
    union { float f; unsigned int u; } v; v.f = f;
    unsigned int r = (v.u + 0x7fffu + ((v.u >> 16) & 1u)) >> 16;
    return (unsigned short)r;
}

// ---------------- elementwise f32 -> bf16 cast ----------------
__global__ void cast_f32_bf16(const float4* __restrict__ in, ushort4* __restrict__ out, int n4) {
    int i = blockIdx.x * blockDim.x + threadIdx.x;
    if (i < n4) {
        float4 v = in[i];
        ushort4 o;
        o.x = f2b(v.x); o.y = f2b(v.y); o.z = f2b(v.z); o.w = f2b(v.w);
        out[i] = o;
    }
}

// ---------------- transpose + cast: in[K][N] f32 -> out[N][K] bf16 ----------------
__global__ void transpose_cast(const float* __restrict__ in, unsigned short* __restrict__ out,
                               int K, int N) {
    __shared__ float tile[32][33];
    int n0 = blockIdx.x * 32, k0 = blockIdx.y * 32;
    int tx = threadIdx.x & 31, ty = threadIdx.x >> 5;
#pragma unroll
    for (int r = 0; r < 32; r += 8)
        tile[ty + r][tx] = in[(k0 + ty + r) * N + n0 + tx];
    __syncthreads();
#pragma unroll
    for (int r = 0; r < 32; r += 8)
        out[(n0 + ty + r) * K + k0 + tx] = f2b(tile[tx][ty + r]);
}

// ---------------- mask layout detection + expansion to float bias ----------------
// context_mask may physically be u8 (numpy bool), i32, or f32. Detect from content,
// expand to bias[s] in {0, -1e38}.
__global__ void mask_expand(const unsigned int* __restrict__ mw, float* __restrict__ bias) {
    __shared__ int flags[2]; // [0]: looks like i32 {0,1}; [1]: looks like f32 {0,1.0f}
    int t = threadIdx.x;
    if (t == 0) { flags[0] = 1; flags[1] = 1; }
    __syncthreads();
    int okI = 1, okF = 1;
    for (int i = t; i < 512; i += 256) {  // first 2048 bytes: safe under every layout
        unsigned int w = mw[i];
        if (w > 1u) okI = 0;
        if (w != 0u && w != 0x3f800000u) okF = 0;
    }
    if (!okI) atomicAnd(&flags[0], 0);
    if (!okF) atomicAnd(&flags[1], 0);
    __syncthreads();
    bool wordLayout = (flags[0] != 0) || (flags[1] != 0);
    const unsigned char* mb = (const unsigned char*)mw;
    for (int s = t; s < BB * SS; s += 256) {
        bool on = wordLayout ? (mw[s] != 0u) : (mb[s] != 0);
        bias[s] = on ? 0.0f : -1e38f;
    }
}

// ---------------- GEMM: C[M][N] = A[M][K] * Bt[N][K]^T (+bias, fused epilogues) ---
// MODE 0: Q-proj   -> out_u16[m][n] = bf16((c+bias[n]) * (0.125*log2e))
// MODE 1: KV-proj  -> n<1024: K[b,h,s,d] bf16 ; n>=1024: Vt[b,h,d,s] bf16
// MODE 2: out-proj -> out_f32[m][n] = c + bias[n]
template <int MODE>
__global__ __launch_bounds__(256, 2)
void gemm_bt(const unsigned short* __restrict__ A, const unsigned short* __restrict__ Bt,
             const float* __restrict__ bias, unsigned short* __restrict__ out_u16,
             float* __restrict__ out_f32, unsigned short* __restrict__ out_v,
             int M, int N, int K) {
    __shared__ __align__(16) unsigned short As[128 * 32];
    __shared__ __align__(16) unsigned short Bs[128 * 32];
    const int tid = threadIdx.x;
    const int w = tid >> 6, l = tid & 63;
    const int quad = l >> 4, col = l & 15;
    const int m0 = blockIdx.x * 128, n0 = blockIdx.y * 128;
    const int wm = (w >> 1) * 64, wn = (w & 1) * 64;

    const f32x4 zero = {0.f, 0.f, 0.f, 0.f};
    f32x4 acc[4][4];
#pragma unroll
    for (int i = 0; i < 4; i++)
#pragma unroll
        for (int j = 0; j < 4; j++) acc[i][j] = zero;

    for (int k0 = 0; k0 < K; k0 += 32) {
        __syncthreads();
#pragma unroll
        for (int j = 0; j < 2; ++j) {
            int idx = j * 2048 + tid * 8;
            int r = idx >> 5, c = idx & 31;
            *(bf16x8*)&As[idx] = *(const bf16x8*)&A[(m0 + r) * K + k0 + c];
            *(bf16x8*)&Bs[idx] = *(const bf16x8*)&Bt[(n0 + r) * K + k0 + c];
        }
        __syncthreads();
        bf16x8 af[4], bfr[4];
#pragma unroll
        for (int i = 0; i < 4; i++) af[i]  = *(const bf16x8*)&As[(wm + i * 16 + col) * 32 + quad * 8];
#pragma unroll
        for (int i = 0; i < 4; i++) bfr[i] = *(const bf16x8*)&Bs[(wn + i * 16 + col) * 32 + quad * 8];
#pragma unroll
        for (int i = 0; i < 4; i++)
#pragma unroll
            for (int j = 0; j < 4; j++) acc[i][j] = MFMA(af[i], bfr[j], acc[i][j]);
    }

    // epilogue — C row = m0+wm+i*16+quad*4+ii, col = n0+wn+j*16+col (guide-verified C/D layout)
#pragma unroll
    for (int i = 0; i < 4; i++) {
#pragma unroll
        for (int j = 0; j < 4; j++) {
            int n = n0 + wn + j * 16 + col;
            int mb = m0 + wm + i * 16 + quad * 4;
            float bv = bias[n];
            f32x4 c = acc[i][j];
            if (MODE == 0) {
                const float QS = 0.125f * 1.4426950408889634f;  // 1/sqrt(Hd) * log2(e)
#pragma unroll
                for (int ii = 0; ii < 4; ii++)
                    out_u16[(mb + ii) * N + n] = f2b((c[ii] + bv) * QS);
            } else if (MODE == 1) {
                if (n < 1024) {
                    int h = n >> 6, d = n & 63;
#pragma unroll
                    for (int ii = 0; ii < 4; ii++) {
                        int m = mb + ii; int b = m >> 9, s = m & 511;
                        out_u16[(((b * NH + h) * SS) + s) * HD + d] = f2b(c[ii] + bv);
                    }
                } else {
                    int q = n - 1024; int h = q >> 6, d = q & 63;
#pragma unroll
                    for (int ii = 0; ii < 4; ii++) {
                        int m = mb + ii; int b = m >> 9, s = m & 511;
                        out_v[(((b * NH + h) * HD) + d) * SS + s] = f2b(c[ii] + bv);
                    }
                }
            } else {
#pragma unroll
                for (int ii = 0; ii < 4; ii++)
                    out_f32[(mb + ii) * N + n] = c[ii] + bv;
            }
        }
    }
}

// ---------------- flash attention: one block = (b, h, 64 T-rows), 4 waves ----------
__global__ __launch_bounds__(256)
void flash_attn(const unsigned short* __restrict__ Q, const unsigned short* __restrict__ Kb,
                const unsigned short* __restrict__ Vt, const float* __restrict__ mbias,
                unsigned short* __restrict__ O) {
    const int bid = blockIdx.x;
    const int tb = bid & 31, bh = bid >> 5;   // T/64 = 32 tiles; bh = b*NH+h
    const int b = bh >> 4;
    const int w = threadIdx.x >> 6, l = threadIdx.x & 63;
    const int quad = l >> 4, col = l & 15;
    __shared__ __align__(16) unsigned short Pb[4][16 * 40]; // per-wave P tile, padded stride 40

    // Q A-fragment (m = col, k = d), held in registers for the whole loop
    const unsigned short* qrow = Q + (b * TT + tb * 64 + w * 16 + col) * DM + (bh & 15) * HD;
    bf16x8 qf0 = *(const bf16x8*)(qrow + quad * 8);
    bf16x8 qf1 = *(const bf16x8*)(qrow + 32 + quad * 8);

    const unsigned short* Kh = Kb + bh * SS * HD;
    const unsigned short* Vh = Vt + bh * HD * SS;
    const float* mrow = mbias + b * SS;

    const f32x4 zero = {0.f, 0.f, 0.f, 0.f};
    f32x4 o0 = zero, o1 = zero, o2 = zero, o3 = zero;
    float mrun[4] = {-1e38f, -1e38f, -1e38f, -1e38f};
    float lrun[4] = {0.f, 0.f, 0.f, 0.f};

    for (int s0 = 0; s0 < SS; s0 += 32) {
        // ---- scores: two 16-wide s-tiles ----
        f32x4 sc0 = zero, sc1 = zero;
        const unsigned short* kp = Kh + (s0 + col) * HD + quad * 8;
        sc0 = MFMA(qf0, *(const bf16x8*)kp, sc0);
        sc0 = MFMA(qf1, *(const bf16x8*)(kp + 32), sc0);
        const unsigned short* kp1 = kp + 16 * HD;
        sc1 = MFMA(qf0, *(const bf16x8*)kp1, sc1);
        sc1 = MFMA(qf1, *(const bf16x8*)(kp1 + 32), sc1);

        float b0 = mrow[s0 + col], b1 = mrow[s0 + 16 + col];
        float alpha[4];
#pragma unroll
        for (int i = 0; i < 4; i++) {
            float v0 = sc0[i] + b0, v1 = sc1[i] + b1;
            float mx = fmaxf(v0, v1);
#pragma unroll
            for (int off = 1; off < 16; off <<= 1) mx = fmaxf(mx, __shfl_xor(mx, off));
            float mn = fmaxf(mrun[i], mx);
            float al = exp2f(mrun[i] - mn);
            mrun[i] = mn;
            float p0 = exp2f(v0 - mn), p1 = exp2f(v1 - mn);
            float rs = p0 + p1;
#pragma unroll
            for (int off = 1; off < 16; off <<= 1) rs += __shfl_xor(rs, off);
            lrun[i] = lrun[i] * al + rs;
            alpha[i] = al;
            Pb[w][(quad * 4 + i) * 40 + col]      = f2b(p0);
            Pb[w][(quad * 4 + i) * 40 + 16 + col] = f2b(p1);
        }
#pragma unroll
        for (int i = 0; i < 4; i++) {
            o0[i] *= alpha[i]; o1[i] *= alpha[i]; o2[i] *= alpha[i]; o3[i] *= alpha[i];
        }
        // P: C-layout -> A-layout via per-wave LDS round trip
        asm volatile("s_waitcnt lgkmcnt(0)" ::: "memory");
        bf16x8 pf = *(const bf16x8*)&Pb[w][col * 40 + quad * 8];
        asm volatile("" ::: "memory");
        // ---- PV: B-frag from Vt[b,h,d,s] is 16B contiguous ----
        const unsigned short* vp = Vh + col * SS + s0 + quad * 8;
        o0 = MFMA(pf, *(const bf16x8*)vp,             o0);
        o1 = MFMA(pf, *(const bf16x8*)(vp + 16 * SS), o1);
        o2 = MFMA(pf, *(const bf16x8*)(vp + 32 * SS), o2);
        o3 = MFMA(pf, *(const bf16x8*)(vp + 48 * SS), o3);
    }

    unsigned short* orow = O + (b * TT + tb * 64 + w * 16 + quad * 4) * DM + (bh & 15) * HD + col;
#pragma unroll
    for (int i = 0; i < 4; i++) {
        float inv = 1.0f / lrun[i];
        orow[i * DM +  0] = f2b(o0[i] * inv);
        orow[i * DM + 16] = f2b(o1[i] * inv);
        orow[i * DM + 32] = f2b(o2[i] * inv);
        orow[i * DM + 48] = f2b(o3[i] * inv);
    }
}

// ---------------- launcher ----------------
extern "C" void kernel_launch(void* const* d_in, const int* in_sizes, int n_in,
                              void* d_out, int out_size, void* d_ws, size_t ws_size,
                              hipStream_t stream) {
    const float* x    = (const float*)d_in[0];
    const float* ctx  = (const float*)d_in[1];
    const void*  cmsk = d_in[2];
    const float* Wq   = (const float*)d_in[3];
    const float* bq   = (const float*)d_in[4];
    const float* Wkv  = (const float*)d_in[5];
    const float* bkv  = (const float*)d_in[6];
    const float* Wp   = (const float*)d_in[7];
    const float* bp   = (const float*)d_in[8];
    float* out = (float*)d_out;

    char* ws = (char*)d_ws;
    size_t off = 0;
    auto alloc = [&](size_t bytes) -> void* {
        void* p = ws + off;
        off += (bytes + 255) & ~(size_t)255;
        return p;
    };
    const size_t NX = (size_t)BB * TT * DM;   // 8388608
    const size_t NC = (size_t)BB * SS * DM;   // 2097152
    unsigned short* Xbf  = (unsigned short*)alloc(NX * 2);
    unsigned short* Cbf  = (unsigned short*)alloc(NC * 2);
    unsigned short* WqT  = (unsigned short*)alloc((size_t)DM * DM * 2);
    unsigned short* WkvT = (unsigned short*)alloc((size_t)DM * 2 * DM * 2);
    unsigned short* WpT  = (unsigned short*)alloc((size_t)DM * DM * 2);
    unsigned short* Qb   = (unsigned short*)alloc(NX * 2);
    unsigned short* Kbf  = (unsigned short*)alloc(NC * 2);
    unsigned short* Vtb  = (unsigned short*)alloc(NC * 2);
    unsigned short* Ob   = (unsigned short*)alloc(NX * 2);
    float* mbias         = (float*)alloc((size_t)BB * SS * 4);

    cast_f32_bf16<<<(NX / 4 + 255) / 256, 256, 0, stream>>>((const float4*)x,  (ushort4*)Xbf, NX / 4);
    cast_f32_bf16<<<(NC / 4 + 255) / 256, 256, 0, stream>>>((const float4*)ctx,(ushort4*)Cbf, NC / 4);
    transpose_cast<<<dim3(32, 32), 256, 0, stream>>>(Wq,  WqT,  DM, DM);
    transpose_cast<<<dim3(64, 32), 256, 0, stream>>>(Wkv, WkvT, DM, 2 * DM);
    transpose_cast<<<dim3(32, 32), 256, 0, stream>>>(Wp,  WpT,  DM, DM);
    mask_expand<<<1, 256, 0, stream>>>((const unsigned int*)cmsk, mbias);

    // Q = (x@Wq + bq) * scale  -> bf16 [B*T][D]
    gemm_bt<0><<<dim3(64, 8), 256, 0, stream>>>(Xbf, WqT, bq, Qb, nullptr, nullptr,
                                                BB * TT, DM, DM);
    // K,V = context@Wkv + bkv -> K[b,h,s,d], Vt[b,h,d,s]
    gemm_bt<1><<<dim3(16, 16), 256, 0, stream>>>(Cbf, WkvT, bkv, Kbf, nullptr, Vtb,
                                                 BB * SS, 2 * DM, DM);
    // attention
    flash_attn<<<BB * NH * (TT / 64), 256, 0, stream>>>(Qb, Kbf, Vtb, mbias, Ob);
    // out = O@Wp + bp (fp32)
    gemm_bt<2><<<dim3(64, 8), 256, 0, stream>>>(Ob, WpT, bp, nullptr, out, nullptr,
                                                BB * TT, DM, DM);
}